// Round 1
// baseline (23418.039 us; speedup 1.0000x reference)
//
#include <hip/hip_runtime.h>
#include <stdint.h>

// Problem dims
#define T_STEPS 512
#define BATCH   64
#define DIN     256
#define HID     512
#define KTOT    768   // DIN + HID
// Team decomposition: 4 teams (one per XCD under round-robin dispatch), each
// owns 16 batch rows and 32 CUs. Each CU owns 16 hidden units (all 4 gates).
#define NTEAMS  4
#define TB      16
#define KK_X    8     // k-tiles (K=32) covering x part
#define KK_H    16    // k-tiles covering h part
#define KK_ALL  24

typedef __bf16 v8bf __attribute__((ext_vector_type(8)));
typedef float  v4f  __attribute__((ext_vector_type(4)));

// workspace layout (bytes)
#define CNT_OFF   0                       // 4 uint counters @ 64B stride
#define HBUF_OFF  256                     // [4 teams][2 parity][16][512] u16 (swizzled image) = 131072
#define WPK_OFF   131584                  // [128 wv][24 kk][64 lane][8] u16 = 3145728
#define XPK_OFF   (WPK_OFF + 3145728)     // [512 t][4 team][8 kk][64 lane][8] u16 = 16777216

static __device__ __forceinline__ unsigned short f2bf(float x) {
  union { float f; uint32_t u; } v; v.f = x;
  uint32_t r = (v.u + 0x7fffu + ((v.u >> 16) & 1u)) >> 16;
  return (unsigned short)r;
}

static __device__ __forceinline__ float sigm(float x) {
  float e = __builtin_amdgcn_exp2f(-1.44269504f * x);
  return __builtin_amdgcn_rcpf(1.0f + e);
}
static __device__ __forceinline__ float tanh_(float x) {
  float e = __builtin_amdgcn_exp2f(2.88539008f * x);   // exp(2x)
  return 1.0f - 2.0f * __builtin_amdgcn_rcpf(e + 1.0f); // inf-safe: -> 1 / -1
}

// ---- Prologue: pack weights into MFMA A-fragment order (bf16) ----
// A-frag (16x16x32): lane l holds A[row=l&15][k=(l>>4)*8 .. +8].
// Row within a wave's 16-row M-tile = u_local*4 + gate (gate: 0=f,1=i,2=g,3=o).
__global__ void pack_w(const float* __restrict__ Wf, const float* __restrict__ Wi,
                       const float* __restrict__ Wg, const float* __restrict__ Wo,
                       unsigned short* __restrict__ wpk) {
  int n = blockIdx.x * 256 + threadIdx.x;           // 128*24*64 = 196608 chunks
  int l  = n & 63;
  int kk = (n >> 6) % KK_ALL;
  int wv = (n >> 6) / KK_ALL;                       // cu*4 + w, 0..127
  int row  = l & 15;
  int gate = row & 3;
  int unit = (wv >> 2) * 16 + (wv & 3) * 4 + (row >> 2);
  int col  = kk * 32 + (l >> 4) * 8;
  const float* W = (gate == 0) ? Wf : (gate == 1) ? Wi : (gate == 2) ? Wg : Wo;
  const float* src = W + (size_t)unit * KTOT + col;
  unsigned short* dst = wpk + (size_t)n * 8;
#pragma unroll
  for (int e = 0; e < 8; e++) dst[e] = f2bf(src[e]);
}

// ---- Prologue: pack x into MFMA B-fragment order (bf16) ----
// B-frag: lane l holds B[k=(l>>4)*8 .. +8][col=l&15]; col = team-local batch.
__global__ void pack_x(const float* __restrict__ X, unsigned short* __restrict__ xpk) {
  int n = blockIdx.x * 256 + threadIdx.x;           // 512*4*8*64 = 1048576 chunks
  int l    = n & 63;
  int kk   = (n >> 6) & 7;
  int team = (n >> 9) & 3;
  int t    = n >> 11;
  int b    = team * TB + (l & 15);
  int col  = kk * 32 + (l >> 4) * 8;
  const float* src = X + ((size_t)(t * BATCH + b)) * DIN + col;
  unsigned short* dst = xpk + (size_t)n * 8;
#pragma unroll
  for (int e = 0; e < 8; e++) dst[e] = f2bf(src[e]);
}

// ---- Persistent recurrent kernel ----
// grid 256 x block 256. team = blk&7 (>=NTEAMS exits), member cu = blk>>3.
__global__ void __launch_bounds__(256, 1)
lstm_rec(const float* __restrict__ bf_, const float* __restrict__ bi_,
         const float* __restrict__ bg_, const float* __restrict__ bo_,
         const unsigned short* __restrict__ wpk, const unsigned short* __restrict__ xpk,
         float* __restrict__ out, unsigned int* cnt, unsigned short* hbuf) {
  int blk  = blockIdx.x;
  int team = blk & 7;
  if (team >= NTEAMS) return;
  int cu  = blk >> 3;              // 0..31
  int tid = threadIdx.x;
  int w   = tid >> 6, l = tid & 63;
  int brow = l & 15;               // team-local batch row (B-frag col / C col)
  int ul   = l >> 4;               // 0..3
  int u    = cu * 16 + w * 4 + ul; // hidden unit owned by this lane
  int bglob = team * TB + brow;

  __shared__ unsigned short hl[TB * HID];   // 16 KB swizzled h image

  // Load stationary weight fragments (96 VGPRs)
  v8bf wf[KK_ALL];
  {
    const unsigned short* wp = wpk + ((size_t)(cu * 4 + w)) * (KK_ALL * 512) + l * 8;
#pragma unroll
    for (int kk = 0; kk < KK_ALL; kk++)
      wf[kk] = *(const v8bf*)(wp + (size_t)kk * 512);
  }
  float b0 = bf_[u], b1 = bi_[u], b2 = bg_[u], b3 = bo_[u];
  float c = 0.0f, hval = 0.0f;

  unsigned int* mycnt = cnt + team * 16;    // 64B stride per team
  float* outb = out + (size_t)bglob * HID + u;

  for (int t = 0; t < T_STEPS; t++) {
    // x-part B-frags (issued before spin: latency overlaps the wait)
    v8bf xf[KK_X];
    {
      const unsigned short* xp = xpk + ((size_t)(t * NTEAMS + team)) * (KK_X * 512) + l * 8;
#pragma unroll
      for (int kk = 0; kk < KK_X; kk++)
        xf[kk] = *(const v8bf*)(xp + (size_t)kk * 512);
    }

    // wait for h_{t-1} from all 32 CUs of this team
    if (t > 0) {
      if (tid == 0) {
        unsigned int tgt = 32u * (unsigned)t;
        while (__hip_atomic_load(mycnt, __ATOMIC_RELAXED, __HIP_MEMORY_SCOPE_AGENT) < tgt) { }
      }
      __syncthreads();
      __threadfence();   // acquire side: invalidate stale caches
    }

    // accumulators: 4 independent chains to pipeline dependent MFMAs
    v4f acc[4];
    acc[0] = (v4f){b0, b1, b2, b3};
    acc[1] = (v4f){0.f, 0.f, 0.f, 0.f};
    acc[2] = (v4f){0.f, 0.f, 0.f, 0.f};
    acc[3] = (v4f){0.f, 0.f, 0.f, 0.f};

#pragma unroll
    for (int kk = 0; kk < KK_X; kk++)
      acc[kk & 3] = __builtin_amdgcn_mfma_f32_16x16x32_bf16(wf[kk], xf[kk], acc[kk & 3], 0, 0, 0);

    // stage h image (16 KB, pre-swizzled in global) linearly into LDS
    {
      const unsigned short* hsrc = hbuf + ((size_t)team * 2 + (size_t)(t & 1)) * (TB * HID);
#pragma unroll
      for (int j = 0; j < 4; j++) {
        int off = w * 4096 + j * 1024 + l * 16;   // bytes; conflict-free pattern
        uint4 v = *(const uint4*)((const char*)hsrc + off);
        *(uint4*)((char*)hl + off) = v;
      }
    }
    __syncthreads();

    // h-part MFMAs from LDS (XOR-swizzled reads, ~2-way bank aliasing = free)
#pragma unroll
    for (int kk = 0; kk < KK_H; kk++) {
      int byte = brow * 1024 + kk * 64 + ul * 16;
      byte ^= (brow & 7) << 4;
      v8bf hf = *(const v8bf*)((const char*)hl + byte);
      acc[kk & 3] = __builtin_amdgcn_mfma_f32_16x16x32_bf16(wf[KK_X + kk], hf, acc[kk & 3], 0, 0, 0);
    }
    v4f g4 = (acc[0] + acc[1]) + (acc[2] + acc[3]);

    // gates are lane-local: acc[r] r=0..3 -> f,i,g,o for (unit u, batch bglob)
    float fg = sigm(g4[0]);
    float ig = sigm(g4[1]);
    float gg = tanh_(g4[2]);
    float og = sigm(g4[3]);
    c    = fg * c + ig * gg;
    hval = og * tanh_(c);

    // outputs[t][b][u]
    outb[(size_t)t * (BATCH * HID)] = hval;

    // publish h into the other parity slab, swizzled image layout
    {
      unsigned short* hdst = hbuf + ((size_t)team * 2 + (size_t)((t + 1) & 1)) * (TB * HID);
      int byte = brow * 1024 + u * 2;
      byte ^= (brow & 7) << 4;
      *(unsigned short*)((char*)hdst + byte) = f2bf(hval);
    }
    __threadfence();     // release side: h visible before arrival
    __syncthreads();     // also: all waves done reading hl before next staging
    if (tid == 0)
      __hip_atomic_fetch_add(mycnt, 1u, __ATOMIC_RELEASE, __HIP_MEMORY_SCOPE_AGENT);
  }

  // final hx, cx
  float* hx = out + (size_t)T_STEPS * BATCH * HID;
  hx[(size_t)bglob * HID + u] = hval;
  float* cx = hx + BATCH * HID;
  cx[(size_t)bglob * HID + u] = c;
}

extern "C" void kernel_launch(void* const* d_in, const int* in_sizes, int n_in,
                              void* d_out, int out_size, void* d_ws, size_t ws_size,
                              hipStream_t stream) {
  const float* X  = (const float*)d_in[0];
  const float* Wf = (const float*)d_in[1];
  const float* bf = (const float*)d_in[2];
  const float* Wi = (const float*)d_in[3];
  const float* bi = (const float*)d_in[4];
  const float* Wg = (const float*)d_in[5];
  const float* bg = (const float*)d_in[6];
  const float* Wo = (const float*)d_in[7];
  const float* bo = (const float*)d_in[8];
  float* out = (float*)d_out;
  char* ws = (char*)d_ws;

  unsigned int*   cnt  = (unsigned int*)(ws + CNT_OFF);
  unsigned short* hbuf = (unsigned short*)(ws + HBUF_OFF);
  unsigned short* wpk  = (unsigned short*)(ws + WPK_OFF);
  unsigned short* xpk  = (unsigned short*)(ws + XPK_OFF);

  // zero counters + h double-buffers every call (graph-replay determinism)
  hipMemsetAsync(ws, 0, WPK_OFF, stream);
  pack_w<<<768, 256, 0, stream>>>(Wf, Wi, Wg, Wo, wpk);
  pack_x<<<4096, 256, 0, stream>>>(X, xpk);
  lstm_rec<<<256, 256, 0, stream>>>(bf, bi, bg, bo, wpk, xpk, out, cnt, hbuf);
}

// Round 2
// 1652.193 us; speedup vs baseline: 14.1739x; 14.1739x over previous
//
#include <hip/hip_runtime.h>
#include <stdint.h>

// Problem dims
#define T_STEPS 512
#define BATCH   64
#define DIN     256
#define HID     512
#define KTOT    768   // DIN + HID
#define NTEAMS  4
#define TB      16
#define KK_X    8     // k-tiles (K=32) covering x part
#define KK_H    16    // k-tiles covering h part
#define KK_ALL  24

typedef __bf16 v8bf __attribute__((ext_vector_type(8)));
typedef float  v4f  __attribute__((ext_vector_type(4)));
typedef unsigned int v4u __attribute__((ext_vector_type(4)));

// workspace layout (bytes)
#define FLAGS_OFF 0                       // [4 team][32 cu] u32 @ 64B stride = 8192
#define HBUF_OFF  8192                    // [4 team][2 parity][16][512] u16 = 131072
#define WPK_OFF   (HBUF_OFF + 131072)     // [128 wv][24 kk][64 lane][8] u16 = 3145728
#define XPK_OFF   (WPK_OFF + 3145728)     // [512 t][4 team][8 kk][64 lane][8] u16 = 16777216

// coherent (Infinity-Cache point) load/store helpers — per-line, NO cache-wide fences
#define LOADH(d, a, IMM) \
  asm volatile("global_load_dwordx4 %0, %1, off offset:" IMM " sc0 sc1" \
               : "=v"(d) : "v"(a) : "memory")
#define STORE_SHORT_C(a, v) \
  asm volatile("global_store_short %0, %1, off sc0 sc1" :: "v"(a), "v"(v) : "memory")
#define STORE_DWORD_C(a, v) \
  asm volatile("global_store_dword %0, %1, off sc0 sc1" :: "v"(a), "v"(v) : "memory")
#define DRAIN_VM() asm volatile("s_waitcnt vmcnt(0)" ::: "memory")

static __device__ __forceinline__ unsigned short f2bf(float x) {
  union { float f; uint32_t u; } v; v.f = x;
  uint32_t r = (v.u + 0x7fffu + ((v.u >> 16) & 1u)) >> 16;
  return (unsigned short)r;
}

static __device__ __forceinline__ float sigm(float x) {
  float e = __builtin_amdgcn_exp2f(-1.44269504f * x);
  return __builtin_amdgcn_rcpf(1.0f + e);
}
static __device__ __forceinline__ float tanh_(float x) {
  float e = __builtin_amdgcn_exp2f(2.88539008f * x);    // exp(2x)
  return 1.0f - 2.0f * __builtin_amdgcn_rcpf(e + 1.0f); // inf-safe -> +/-1
}

// ---- Prologue: pack weights into MFMA A-fragment order (bf16) ----
__global__ void pack_w(const float* __restrict__ Wf, const float* __restrict__ Wi,
                       const float* __restrict__ Wg, const float* __restrict__ Wo,
                       unsigned short* __restrict__ wpk) {
  int n = blockIdx.x * 256 + threadIdx.x;           // 128*24*64 = 196608 chunks
  int l  = n & 63;
  int kk = (n >> 6) % KK_ALL;
  int wv = (n >> 6) / KK_ALL;                       // cu*4 + w, 0..127
  int row  = l & 15;
  int gate = row & 3;
  int unit = (wv >> 2) * 16 + (wv & 3) * 4 + (row >> 2);
  int col  = kk * 32 + (l >> 4) * 8;
  const float* W = (gate == 0) ? Wf : (gate == 1) ? Wi : (gate == 2) ? Wg : Wo;
  const float* src = W + (size_t)unit * KTOT + col;
  unsigned short* dst = wpk + (size_t)n * 8;
#pragma unroll
  for (int e = 0; e < 8; e++) dst[e] = f2bf(src[e]);
}

// ---- Prologue: pack x into MFMA B-fragment order (bf16) ----
__global__ void pack_x(const float* __restrict__ X, unsigned short* __restrict__ xpk) {
  int n = blockIdx.x * 256 + threadIdx.x;           // 512*4*8*64 = 1048576 chunks
  int l    = n & 63;
  int kk   = (n >> 6) & 7;
  int team = (n >> 9) & 3;
  int t    = n >> 11;
  int b    = team * TB + (l & 15);
  int col  = kk * 32 + (l >> 4) * 8;
  const float* src = X + ((size_t)(t * BATCH + b)) * DIN + col;
  unsigned short* dst = xpk + (size_t)n * 8;
#pragma unroll
  for (int e = 0; e < 8; e++) dst[e] = f2bf(src[e]);
}

// ---- Persistent recurrent kernel ----
// grid 256 x block 256. team = blk&7 (>=NTEAMS exits), member cu = blk>>3.
__global__ void __launch_bounds__(256, 1)
lstm_rec(const float* __restrict__ bf_, const float* __restrict__ bi_,
         const float* __restrict__ bg_, const float* __restrict__ bo_,
         const unsigned short* __restrict__ wpk, const unsigned short* __restrict__ xpk,
         float* __restrict__ out, unsigned int* flags, unsigned short* hbuf) {
  int blk  = blockIdx.x;
  int team = blk & 7;
  if (team >= NTEAMS) return;
  int cu  = blk >> 3;              // 0..31
  int tid = threadIdx.x;
  int w   = tid >> 6, l = tid & 63;
  int brow = l & 15;               // team-local batch row (B-frag col / C col)
  int ul   = l >> 4;               // 0..3
  int u    = cu * 16 + w * 4 + ul; // hidden unit owned by this lane
  int bglob = team * TB + brow;

  // stationary weight fragments, pinned resident (96 VGPRs)
  v4u wfu[KK_ALL];
  {
    const v4u* wp = (const v4u*)(wpk + ((size_t)(cu * 4 + w)) * (KK_ALL * 512) + l * 8);
#pragma unroll
    for (int kk = 0; kk < KK_ALL; kk++) wfu[kk] = wp[kk * 64];
#pragma unroll
    for (int kk = 0; kk < KK_ALL; kk++) asm volatile("" : "+v"(wfu[kk]));
  }
  float b0 = bf_[u], b1 = bi_[u], b2 = bg_[u], b3 = bo_[u];
  float c = 0.0f, hval = 0.0f;

  // h-image pointers (parity double buffer), consumer + producer sides
  char* slab0 = (char*)(hbuf + (size_t)team * 2 * (TB * HID));
  char* slab1 = slab0 + TB * HID * 2;
  const char* cons0 = slab0 + brow * 1024 + ul * 16;
  const char* cons1 = slab1 + brow * 1024 + ul * 16;
  char* pub0 = slab0 + brow * 1024 + u * 2;
  char* pub1 = slab1 + brow * 1024 + u * 2;

  unsigned int* ftm = flags + (size_t)team * 32 * 16;  // this team's 32 CU flags
  unsigned int* myflag = ftm + (size_t)cu * 16;
  const unsigned int* pollp = ftm + (size_t)(l & 31) * 16;

  float* outb = out + (size_t)bglob * HID + u;

  for (int t = 0; t < T_STEPS; t++) {
    // x-part B-frags: plain cached loads (xpk is read-only, L2-resident)
    v8bf xf[KK_X];
    {
      const v8bf* xp = (const v8bf*)(xpk + ((size_t)(t * NTEAMS + team)) * (KK_X * 512) + l * 8);
#pragma unroll
      for (int kk = 0; kk < KK_X; kk++) xf[kk] = xp[kk * 64];
    }

    // wait until all 32 CUs of this team have published h_t
    if (t > 0) {
      if (w == 0) {
        while (true) {
          unsigned int v = __hip_atomic_load(pollp, __ATOMIC_RELAXED, __HIP_MEMORY_SCOPE_AGENT);
          if (__all(v >= (unsigned)t)) break;
        }
      }
      __syncthreads();
    }

    // h B-frags straight from the coherence point (16 x 16B per lane)
    const char* cb = (t & 1) ? cons1 : cons0;
    v4u hf[16];
    LOADH(hf[0],  cb, "0");   LOADH(hf[1],  cb, "64");
    LOADH(hf[2],  cb, "128"); LOADH(hf[3],  cb, "192");
    LOADH(hf[4],  cb, "256"); LOADH(hf[5],  cb, "320");
    LOADH(hf[6],  cb, "384"); LOADH(hf[7],  cb, "448");
    LOADH(hf[8],  cb, "512"); LOADH(hf[9],  cb, "576");
    LOADH(hf[10], cb, "640"); LOADH(hf[11], cb, "704");
    LOADH(hf[12], cb, "768"); LOADH(hf[13], cb, "832");
    LOADH(hf[14], cb, "896"); LOADH(hf[15], cb, "960");

    // x-part MFMAs overlap the h-load latency
    v4f acc[4];
    acc[0] = (v4f){b0, b1, b2, b3};
    acc[1] = (v4f){0.f, 0.f, 0.f, 0.f};
    acc[2] = (v4f){0.f, 0.f, 0.f, 0.f};
    acc[3] = (v4f){0.f, 0.f, 0.f, 0.f};
#pragma unroll
    for (int kk = 0; kk < KK_X; kk++)
      acc[kk & 3] = __builtin_amdgcn_mfma_f32_16x16x32_bf16(
          __builtin_bit_cast(v8bf, wfu[kk]), xf[kk], acc[kk & 3], 0, 0, 0);

    DRAIN_VM();                          // h frags complete
    __builtin_amdgcn_sched_barrier(0);   // rule #18: no MFMA hoisting above the wait

#pragma unroll
    for (int kk = 0; kk < KK_H; kk++)
      acc[kk & 3] = __builtin_amdgcn_mfma_f32_16x16x32_bf16(
          __builtin_bit_cast(v8bf, wfu[KK_X + kk]),
          __builtin_bit_cast(v8bf, hf[kk]), acc[kk & 3], 0, 0, 0);

    v4f g4 = (acc[0] + acc[1]) + (acc[2] + acc[3]);

    // gates are lane-local: f,i,g,o for (unit u, batch bglob)
    float fg = sigm(g4[0]);
    float ig = sigm(g4[1]);
    float gg = tanh_(g4[2]);
    float og = sigm(g4[3]);
    c    = fg * c + ig * gg;
    hval = og * tanh_(c);

    // outputs[t][b][u] — plain cached store
    outb[(size_t)t * (BATCH * HID)] = hval;

    // publish h_{t+1} write-through, drain, then arrive
    {
      char* pd = ((t + 1) & 1) ? pub1 : pub0;
      unsigned int hb = f2bf(hval);
      STORE_SHORT_C(pd, hb);
    }
    DRAIN_VM();          // per-wave: publish (and out) at coherence point
    __syncthreads();     // all 4 waves drained
    if (tid == 0) {
      unsigned int fv = (unsigned)(t + 1);
      STORE_DWORD_C(myflag, fv);
    }
  }

  // final hx, cx
  float* hx = out + (size_t)T_STEPS * BATCH * HID;
  hx[(size_t)bglob * HID + u] = hval;
  float* cx = hx + BATCH * HID;
  cx[(size_t)bglob * HID + u] = c;
}

extern "C" void kernel_launch(void* const* d_in, const int* in_sizes, int n_in,
                              void* d_out, int out_size, void* d_ws, size_t ws_size,
                              hipStream_t stream) {
  const float* X  = (const float*)d_in[0];
  const float* Wf = (const float*)d_in[1];
  const float* bf = (const float*)d_in[2];
  const float* Wi = (const float*)d_in[3];
  const float* bi = (const float*)d_in[4];
  const float* Wg = (const float*)d_in[5];
  const float* bg = (const float*)d_in[6];
  const float* Wo = (const float*)d_in[7];
  const float* bo = (const float*)d_in[8];
  float* out = (float*)d_out;
  char* ws = (char*)d_ws;

  unsigned int*   flags = (unsigned int*)(ws + FLAGS_OFF);
  unsigned short* hbuf  = (unsigned short*)(ws + HBUF_OFF);
  unsigned short* wpk   = (unsigned short*)(ws + WPK_OFF);
  unsigned short* xpk   = (unsigned short*)(ws + XPK_OFF);

  // zero flags + h double-buffers every call (graph-replay determinism)
  hipMemsetAsync(ws, 0, WPK_OFF, stream);
  pack_w<<<768, 256, 0, stream>>>(Wf, Wi, Wg, Wo, wpk);
  pack_x<<<4096, 256, 0, stream>>>(X, xpk);
  lstm_rec<<<256, 256, 0, stream>>>(bf, bi, bg, bo, wpk, xpk, out, flags, hbuf);
}

// Round 5
// 1348.321 us; speedup vs baseline: 17.3683x; 1.2254x over previous
//
#include <hip/hip_runtime.h>
#include <stdint.h>

// Problem dims
#define T_STEPS 512
#define BATCH   64
#define DIN     256
#define HID     512
#define KTOT    768   // DIN + HID
#define NTEAMS  4
#define TB      16
#define KK_X    8     // k-tiles (K=32) covering x part
#define KK_H    16    // k-tiles covering h part
#define KK_ALL  24

// bounded spin: convert any protocol failure into a terminating wrong answer
#define POLL_BOUND (1 << 18)

typedef __bf16 v8bf __attribute__((ext_vector_type(8)));
typedef float  v4f  __attribute__((ext_vector_type(4)));
typedef unsigned int v4u __attribute__((ext_vector_type(4)));
typedef unsigned int v2u __attribute__((ext_vector_type(2)));

// workspace layout (bytes)
#define FLAGS_OFF 0                       // [4 team][32 cu] u32 @ 64B stride = 8192
#define HBUF_OFF  8192                    // [4 team][2 parity][16][512] u16 = 131072
#define WPK_OFF   (HBUF_OFF + 131072)     // [128 wv][24 kk][64 lane][8] u16 = 3145728
#define XPK_OFF   (WPK_OFF + 3145728)     // [512 t][4 team][8 kk][64 lane][8] u16 = 16777216

// ---- single-instruction asm memory helpers ----
// DEVICE scope = sc1 only: coherent at the Infinity Cache (the cross-XCD
// coherence point). NOT sc0+sc1 (= system scope -> HBM round trips, R2's
// hidden cost), NOT sc0 only (= SE scope, R4's stale-read bug).
#define LOADX4_DEV(d, a, IMM) \
  asm volatile("global_load_dwordx4 %0, %1, off offset:" IMM " sc1" \
               : "=v"(d) : "v"(a) : "memory")
#define ST2_DEV(a, v) \
  asm volatile("global_store_dwordx2 %0, %1, off sc1" :: "v"(a), "v"(v) : "memory")
#define ST_DW_DEV(a, v) \
  asm volatile("global_store_dword %0, %1, off sc1" :: "v"(a), "v"(v) : "memory")
#define LOADX4(d, a) \
  asm volatile("global_load_dwordx4 %0, %1, off" : "=v"(d) : "v"(a) : "memory")
#define DRAIN_VM() asm volatile("s_waitcnt vmcnt(0)" ::: "memory")

static __device__ __forceinline__ unsigned int ld_flag_dev(const unsigned int* p) {
  unsigned int v;
  asm volatile("global_load_dword %0, %1, off sc1\n\ts_waitcnt vmcnt(0)"
               : "=v"(v) : "v"(p) : "memory");
  return v;
}

static __device__ __forceinline__ unsigned short f2bf(float x) {
  union { float f; uint32_t u; } v; v.f = x;
  uint32_t r = (v.u + 0x7fffu + ((v.u >> 16) & 1u)) >> 16;
  return (unsigned short)r;
}

static __device__ __forceinline__ float sigm(float x) {
  float e = __builtin_amdgcn_exp2f(-1.44269504f * x);
  return __builtin_amdgcn_rcpf(1.0f + e);
}
static __device__ __forceinline__ float tanh_(float x) {
  float e = __builtin_amdgcn_exp2f(2.88539008f * x);    // exp(2x)
  return 1.0f - 2.0f * __builtin_amdgcn_rcpf(e + 1.0f); // inf-safe -> +/-1
}

// ---- Prologue: pack weights into MFMA A-fragment order (bf16) ----
__global__ void pack_w(const float* __restrict__ Wf, const float* __restrict__ Wi,
                       const float* __restrict__ Wg, const float* __restrict__ Wo,
                       unsigned short* __restrict__ wpk) {
  int n = blockIdx.x * 256 + threadIdx.x;           // 128*24*64 = 196608 chunks
  int l  = n & 63;
  int kk = (n >> 6) % KK_ALL;
  int wv = (n >> 6) / KK_ALL;                       // cu*4 + w, 0..127
  int row  = l & 15;
  int gate = row & 3;
  int unit = (wv >> 2) * 16 + (wv & 3) * 4 + (row >> 2);
  int col  = kk * 32 + (l >> 4) * 8;
  const float* W = (gate == 0) ? Wf : (gate == 1) ? Wi : (gate == 2) ? Wg : Wo;
  const float* src = W + (size_t)unit * KTOT + col;
  unsigned short* dst = wpk + (size_t)n * 8;
#pragma unroll
  for (int e = 0; e < 8; e++) dst[e] = f2bf(src[e]);
}

// ---- Prologue: pack x into MFMA B-fragment order (bf16) ----
__global__ void pack_x(const float* __restrict__ X, unsigned short* __restrict__ xpk) {
  int n = blockIdx.x * 256 + threadIdx.x;           // 512*4*8*64 = 1048576 chunks
  int l    = n & 63;
  int kk   = (n >> 6) & 7;
  int team = (n >> 9) & 3;
  int t    = n >> 11;
  int b    = team * TB + (l & 15);
  int col  = kk * 32 + (l >> 4) * 8;
  const float* src = X + ((size_t)(t * BATCH + b)) * DIN + col;
  unsigned short* dst = xpk + (size_t)n * 8;
#pragma unroll
  for (int e = 0; e < 8; e++) dst[e] = f2bf(src[e]);
}

// ---- Persistent recurrent kernel ----
// grid 256 x block 256. team = blk&7 (>=NTEAMS exits), member cu = blk>>3.
// Device-scope (sc1 / Infinity-Cache) handshake, correct under ANY placement.
__global__ void __launch_bounds__(256, 1)
lstm_rec(const float* __restrict__ bf_, const float* __restrict__ bi_,
         const float* __restrict__ bg_, const float* __restrict__ bo_,
         const unsigned short* __restrict__ wpk, const unsigned short* __restrict__ xpk,
         float* __restrict__ out, unsigned int* flags, unsigned short* hbuf) {
  int blk  = blockIdx.x;
  int team = blk & 7;
  if (team >= NTEAMS) return;
  int cu  = blk >> 3;              // 0..31
  int tid = threadIdx.x;
  int w   = tid >> 6, l = tid & 63;
  int brow = l & 15;               // team-local batch row (B-frag col / C col)
  int ul   = l >> 4;               // 0..3
  int u    = cu * 16 + w * 4 + ul; // hidden unit owned by this lane
  int bglob = team * TB + brow;

  __shared__ v4u hls[1024];        // 16 KB swizzled h image
  char* hl = (char*)hls;

  // stationary weight fragments via asm loads (non-rematerializable
  // => forced resident in VGPRs, ~96 regs)
  v4u wfu[KK_ALL];
  {
    const char* wp = (const char*)(wpk + ((size_t)(cu * 4 + w)) * (KK_ALL * 512) + l * 8);
#pragma unroll
    for (int kk = 0; kk < KK_ALL; kk++) LOADX4(wfu[kk], wp + (size_t)kk * 1024);
    DRAIN_VM();
  }
  float b0 = bf_[u], b1 = bi_[u], b2 = bg_[u], b3 = bo_[u];
  float c = 0.0f, hval = 0.0f;

  // h-slab pointers (parity double buffer), linear [brow][unit] u16 rows of 1024B
  char* slab0 = (char*)(hbuf + (size_t)team * 2 * (TB * HID));
  char* slab1 = slab0 + TB * HID * 2;

  unsigned int* ftm = flags + (size_t)team * 32 * 16;  // this team's 32 CU flags
  unsigned int* myflag = ftm + (size_t)cu * 16;

  float* outb = out + (size_t)bglob * HID + u;

  for (int t = 0; t < T_STEPS; t++) {
    // x-part B-frags: plain cached loads (xpk read-only, L2-resident)
    v8bf xf[KK_X];
    {
      const v8bf* xp = (const v8bf*)(xpk + ((size_t)(t * NTEAMS + team)) * (KK_X * 512) + l * 8);
#pragma unroll
      for (int kk = 0; kk < KK_X; kk++) xf[kk] = xp[kk * 64];
    }

    // wait until all 32 CUs of this team have published h_t
    if (t > 0) {
      if (w == 0) {
        const unsigned int* pp = ftm + (size_t)(l & 31) * 16;
        int guard = 0;
        while (true) {
          unsigned int v = ld_flag_dev(pp);
          if (__all(v >= (unsigned)t)) break;
          if (++guard > POLL_BOUND) break;   // degrade, never hang
        }
      }
      __syncthreads();
    }

    // stage this wave's quarter of the h image (4KB): rows w*4..w*4+3
    v4u s0, s1, s2, s3;
    {
      const char* sb = ((t & 1) ? slab1 : slab0) + w * 4096 + l * 16;
      LOADX4_DEV(s0, sb, "0");
      LOADX4_DEV(s1, sb, "1024");
      LOADX4_DEV(s2, sb, "2048");
      LOADX4_DEV(s3, sb, "3072");
    }

    // x-part MFMAs overlap the stage-load latency
    v4f acc[4];
    acc[0] = (v4f){b0, b1, b2, b3};
    acc[1] = (v4f){0.f, 0.f, 0.f, 0.f};
    acc[2] = (v4f){0.f, 0.f, 0.f, 0.f};
    acc[3] = (v4f){0.f, 0.f, 0.f, 0.f};
#pragma unroll
    for (int kk = 0; kk < KK_X; kk++)
      acc[kk & 3] = __builtin_amdgcn_mfma_f32_16x16x32_bf16(
          __builtin_bit_cast(v8bf, wfu[kk]), xf[kk], acc[kk & 3], 0, 0, 0);

    DRAIN_VM();                          // stage loads complete
    __builtin_amdgcn_sched_barrier(0);   // rule #18

    // LDS writes with XOR swizzle: byte ^= (row&7)<<4
    {
      int r = w * 4;
      *(v4u*)(hl + (((r + 0) * 1024 + l * 16) ^ (((r + 0) & 7) << 4))) = s0;
      *(v4u*)(hl + (((r + 1) * 1024 + l * 16) ^ (((r + 1) & 7) << 4))) = s1;
      *(v4u*)(hl + (((r + 2) * 1024 + l * 16) ^ (((r + 2) & 7) << 4))) = s2;
      *(v4u*)(hl + (((r + 3) * 1024 + l * 16) ^ (((r + 3) & 7) << 4))) = s3;
    }
    __syncthreads();

    // h-part MFMAs from LDS (swizzled reads)
#pragma unroll
    for (int kk = 0; kk < KK_H; kk++) {
      int off = (brow * 1024 + kk * 64 + ul * 16) ^ ((brow & 7) << 4);
      v8bf hf = *(const v8bf*)(hl + off);
      acc[kk & 3] = __builtin_amdgcn_mfma_f32_16x16x32_bf16(
          __builtin_bit_cast(v8bf, wfu[KK_X + kk]), hf, acc[kk & 3], 0, 0, 0);
    }
    v4f g4 = (acc[0] + acc[1]) + (acc[2] + acc[3]);

    // gates are lane-local: f,i,g,o for (unit u, batch bglob)
    float fg = sigm(g4[0]);
    float ig = sigm(g4[1]);
    float gg = tanh_(g4[2]);
    float og = sigm(g4[3]);
    c    = fg * c + ig * gg;
    hval = og * tanh_(c);

    if (t < T_STEPS - 1) {
      // publish h_{t+1}: pack this wave's 4 units per brow into 8B, 16 lanes store
      float h0 = __shfl(hval, brow);
      float h1 = __shfl(hval, brow + 16);
      float h2 = __shfl(hval, brow + 32);
      float h3 = __shfl(hval, brow + 48);
      if (l < 16) {
        v2u pk;
        pk.x = (unsigned)f2bf(h0) | ((unsigned)f2bf(h1) << 16);
        pk.y = (unsigned)f2bf(h2) | ((unsigned)f2bf(h3) << 16);
        char* pd = (((t + 1) & 1) ? slab1 : slab0) + brow * 1024 + cu * 32 + w * 8;
        ST2_DEV(pd, pk);
      }
      DRAIN_VM();          // publish acked at device coherence point
      __syncthreads();     // all 4 waves drained
      if (tid == 0) ST_DW_DEV(myflag, (unsigned)(t + 1));
    }

    // outputs[t][b][u] — plain cached store, off the publish->flag critical path
    outb[(size_t)t * (BATCH * HID)] = hval;
  }

  // final hx, cx
  float* hx = out + (size_t)T_STEPS * BATCH * HID;
  hx[(size_t)bglob * HID + u] = hval;
  float* cx = hx + BATCH * HID;
  cx[(size_t)bglob * HID + u] = c;
}

extern "C" void kernel_launch(void* const* d_in, const int* in_sizes, int n_in,
                              void* d_out, int out_size, void* d_ws, size_t ws_size,
                              hipStream_t stream) {
  const float* X  = (const float*)d_in[0];
  const float* Wf = (const float*)d_in[1];
  const float* bf = (const float*)d_in[2];
  const float* Wi = (const float*)d_in[3];
  const float* bi = (const float*)d_in[4];
  const float* Wg = (const float*)d_in[5];
  const float* bg = (const float*)d_in[6];
  const float* Wo = (const float*)d_in[7];
  const float* bo = (const float*)d_in[8];
  float* out = (float*)d_out;
  char* ws = (char*)d_ws;

  unsigned int*   flags = (unsigned int*)(ws + FLAGS_OFF);
  unsigned short* hbuf  = (unsigned short*)(ws + HBUF_OFF);
  unsigned short* wpk   = (unsigned short*)(ws + WPK_OFF);
  unsigned short* xpk   = (unsigned short*)(ws + XPK_OFF);

  // zero flags + h double-buffers every call (graph-replay determinism)
  hipMemsetAsync(ws, 0, WPK_OFF, stream);
  pack_w<<<768, 256, 0, stream>>>(Wf, Wi, Wg, Wo, wpk);
  pack_x<<<4096, 256, 0, stream>>>(X, xpk);
  lstm_rec<<<256, 256, 0, stream>>>(bf, bi, bg, bo, wpk, xpk, out, flags, hbuf);
}